// Round 10
// baseline (301.504 us; speedup 1.0000x reference)
//
#include <hip/hip_runtime.h>
#include <stdint.h>

// GCN on MI355X, graph-capture safe. Dataset observed fp32 (flag=0);
// bf16 path kept. Pipeline: detect -> coarse hist -> cscan -> partA
// (radix partition) -> partB (per-bucket CSR) -> wprep2 (fp32 blob +
// MFMA B-frags for W1/W2/Wout) -> mgemm1 (bf16 MFMA, LDS-staged A)
// -> pull1 -> mgemm2 -> pull2 -> k_out (MFMA head + shfl softmax).
// R10: k_pull rewritten to uint4 gathers (8 edges/instr, 1 KB/instr),
// edge-slot partial sums + 3-step shfl_xor reduction per node.

typedef unsigned short u16;
typedef unsigned int u32;
typedef __attribute__((ext_vector_type(8))) short bf16x8;
typedef __attribute__((ext_vector_type(4))) float f32x4;

#define GN 100000
#define GE 1600000
#define NBKT 196  // ceil(100000/512)

__device__ __forceinline__ float bf2f(u32 lo16) {
  union { u32 i; float f; } v; v.i = lo16 << 16; return v.f;
}
__device__ __forceinline__ u16 f2bf(float f) {
  union { float f; u32 i; } v; v.f = f;
  u32 x = v.i;
  u32 r = x + 0x7fffu + ((x >> 16) & 1u);  // RNE
  return (u16)(r >> 16);
}
__device__ __forceinline__ u32 pack2(float a, float b) {
  return (u32)f2bf(a) | ((u32)f2bf(b) << 16);
}

// ---------- dtype sniff (flag=1 -> bf16) + zero coarse counters ----------
__global__ __launch_bounds__(256) void k_detect(const u16* __restrict__ xs,
                                                int* __restrict__ flag,
                                                int* __restrict__ ccount) {
  __shared__ int cnt;
  if (threadIdx.x == 0) cnt = 0;
  if (threadIdx.x < NBKT) ccount[threadIdx.x] = 0;
  __syncthreads();
  int w = 0;
#pragma unroll
  for (int i = 0; i < 16; i++) {
    int s = threadIdx.x * 16 + i;
    u32 u = xs[(size_t)s * 1562];
    u32 ex = (u >> 7) & 0xffu;
    if (ex == 0xffu || ex < 0x40u) w++;
  }
  atomicAdd(&cnt, w);
  __syncthreads();
  if (threadIdx.x == 0) flag[0] = (cnt >= 64) ? 0 : 1;
}

// ---------- coarse histogram over dst>>9 ----------
__global__ __launch_bounds__(256) void k_coarse(const int* __restrict__ dst,
                                                int* __restrict__ ccount, int E) {
  __shared__ int hist[256];
  int tid = threadIdx.x;
  hist[tid] = 0;
  __syncthreads();
  int e0 = (blockIdx.x * 256 + tid) * 8;
  if (e0 + 8 <= E) {
    const int4* dp = (const int4*)(dst + e0);
    int4 a = dp[0], b = dp[1];
    atomicAdd(&hist[a.x >> 9], 1); atomicAdd(&hist[a.y >> 9], 1);
    atomicAdd(&hist[a.z >> 9], 1); atomicAdd(&hist[a.w >> 9], 1);
    atomicAdd(&hist[b.x >> 9], 1); atomicAdd(&hist[b.y >> 9], 1);
    atomicAdd(&hist[b.z >> 9], 1); atomicAdd(&hist[b.w >> 9], 1);
  } else {
    for (int q = 0; q < 8 && e0 + q < E; q++)
      atomicAdd(&hist[dst[e0 + q] >> 9], 1);
  }
  __syncthreads();
  if (tid < NBKT && hist[tid]) atomicAdd(&ccount[tid], hist[tid]);
}

// ---------- scan coarse counts -> cbase (exclusive), cfill ----------
__global__ __launch_bounds__(256) void k_cscan(const int* __restrict__ ccount,
                                               int* __restrict__ cbase,
                                               int* __restrict__ cfill) {
  __shared__ int lds[256];
  int tid = threadIdx.x;
  int v = (tid < NBKT) ? ccount[tid] : 0;
  lds[tid] = v;
  __syncthreads();
#pragma unroll
  for (int off = 1; off < 256; off <<= 1) {
    int a = (tid >= off) ? lds[tid - off] : 0;
    __syncthreads();
    lds[tid] += a;
    __syncthreads();
  }
  int excl = lds[tid] - v;
  if (tid < NBKT) { cbase[tid] = excl; cfill[tid] = excl; }
  if (tid == 255) cbase[NBKT] = lds[255];  // == E
}

// ---------- phase A: partition (src,dst) pairs into coarse-bucket regions --
__global__ __launch_bounds__(256) void k_partA(const int* __restrict__ src,
                                               const int* __restrict__ dst,
                                               int* __restrict__ cfill,
                                               uint2* __restrict__ pairs, int E) {
  __shared__ int hist[256];
  __shared__ int off[256];
  int tid = threadIdx.x;
  hist[tid] = 0;
  __syncthreads();
  int e0 = (blockIdx.x * 256 + tid) * 8;
  int s_[8], d_[8];
  int cnt = 0;
  if (e0 + 8 <= E) {
    const int4* sp = (const int4*)(src + e0);
    const int4* dp = (const int4*)(dst + e0);
#pragma unroll
    for (int q = 0; q < 2; q++) {
      int4 sv = sp[q], dv = dp[q];
      s_[4 * q + 0] = sv.x; s_[4 * q + 1] = sv.y;
      s_[4 * q + 2] = sv.z; s_[4 * q + 3] = sv.w;
      d_[4 * q + 0] = dv.x; d_[4 * q + 1] = dv.y;
      d_[4 * q + 2] = dv.z; d_[4 * q + 3] = dv.w;
    }
    cnt = 8;
  } else {
    for (int q = 0; q < 8 && e0 + q < E; q++) {
      s_[q] = src[e0 + q]; d_[q] = dst[e0 + q]; cnt++;
    }
  }
  for (int q = 0; q < cnt; q++) atomicAdd(&hist[d_[q] >> 9], 1);
  __syncthreads();
  if (tid < NBKT && hist[tid] > 0) off[tid] = atomicAdd(&cfill[tid], hist[tid]);
  __syncthreads();
  for (int q = 0; q < cnt; q++) {
    int bkt = d_[q] >> 9;
    int pos = atomicAdd(&off[bkt], 1);
    pairs[pos] = make_uint2((u32)s_[q], (u32)d_[q]);
  }
}

// ---------- phase B: per-bucket node hist + scan -> rp/dinv; place ssort ---
__global__ __launch_bounds__(256) void k_partB(const uint2* __restrict__ pairs,
                                               const int* __restrict__ cbase,
                                               int* __restrict__ rp,
                                               float* __restrict__ dinv,
                                               int* __restrict__ ssort, int N) {
  __shared__ int cnt[512];
  __shared__ int sc[256];
  int b = blockIdx.x;
  int tid = threadIdx.x;
  int nb0 = b << 9;
  int beg = cbase[b], end = cbase[b + 1];
  cnt[tid] = 0; cnt[tid + 256] = 0;
  __syncthreads();
  for (int i = beg + tid; i < end; i += 256) {
    uint2 p = pairs[i];
    atomicAdd(&cnt[(int)p.y - nb0], 1);
  }
  __syncthreads();
  int c0 = cnt[2 * tid], c1 = cnt[2 * tid + 1];
  int s = c0 + c1;
  sc[tid] = s;
  __syncthreads();
#pragma unroll
  for (int off = 1; off < 256; off <<= 1) {
    int a = (tid >= off) ? sc[tid - off] : 0;
    __syncthreads();
    sc[tid] += a;
    __syncthreads();
  }
  int excl = sc[tid] - s;
  cnt[2 * tid] = excl;
  cnt[2 * tid + 1] = excl + c0;
  int n0 = nb0 + 2 * tid, n1 = n0 + 1;
  if (n0 < N) { rp[n0] = beg + excl;      dinv[n0] = rsqrtf((float)c0 + 1.0f); }
  if (n1 < N) { rp[n1] = beg + excl + c0; dinv[n1] = rsqrtf((float)c1 + 1.0f); }
  if (b == NBKT - 1 && tid == 0) rp[N] = end;
  __syncthreads();
  for (int i = beg + tid; i < end; i += 256) {
    uint2 p = pairs[i];
    int pos = beg + atomicAdd(&cnt[(int)p.y - nb0], 1);
    ssort[pos] = (int)p.x;
  }
}

// ---------- weight prep: fp32 blob + MFMA B-frags (W1, W2, Wout) ----------
__global__ __launch_bounds__(256) void k_wprep2(const void* p2, const void* p3,
                                                const void* p4, const void* p5,
                                                const void* p6, const void* p7,
                                                const int* __restrict__ flag,
                                                float* __restrict__ Wf,
                                                u16* __restrict__ Wb1,
                                                u16* __restrict__ Wb2,
                                                u16* __restrict__ Wbo) {
  int i = blockIdx.x * 256 + threadIdx.x;
  bool isbf = flag[0] != 0;
  if (i < 14496) {
    const void* src; int off;
    if (i < 8192)       { src = p2; off = i; }
    else if (i < 8256)  { src = p3; off = i - 8192; }
    else if (i < 12352) { src = p4; off = i - 8256; }
    else if (i < 12416) { src = p5; off = i - 12352; }
    else if (i < 14464) { src = p6; off = i - 12416; }
    else                { src = p7; off = i - 14464; }
    Wf[i] = isbf ? bf2f((u32)((const u16*)src)[off]) : ((const float*)src)[off];
  } else if (i < 14496 + 12288) {
    int idx = i - 14496;
    const void* W; u16* dst;
    if (idx < 8192) { W = p2; dst = Wb1; }
    else            { W = p4; dst = Wb2; idx -= 8192; }
    int j  = idx & 7;
    int l  = (idx >> 3) & 63;
    int c  = (idx >> 9) & 3;
    int kc = idx >> 11;
    int k = kc * 32 + (l >> 4) * 8 + j;
    int n = c * 16 + (l & 15);
    dst[idx] = isbf ? ((const u16*)W)[k * 64 + n]
                    : f2bf(((const float*)W)[k * 64 + n]);
  } else if (i < 14496 + 12288 + 2048) {
    int idx = i - 14496 - 12288;
    int j  = idx & 7;
    int l  = (idx >> 3) & 63;
    int c  = (idx >> 9) & 1;
    int kc = idx >> 10;
    int k = kc * 32 + (l >> 4) * 8 + j;
    int n = c * 16 + (l & 15);
    Wbo[idx] = isbf ? ((const u16*)p6)[k * 32 + n]
                    : f2bf(((const float*)p6)[k * 32 + n]);
  }
}

// ---------- MFMA GEMM: out[M,64] = bf16(dinv .* (X[M,K]@W[K,64])) ----------
template <int K, int XMODE>
__global__ __launch_bounds__(256) void k_mgemm(const void* __restrict__ X,
                                               const u16* __restrict__ Wb,
                                               const float* __restrict__ dinv,
                                               const int* __restrict__ flag,
                                               u16* __restrict__ out, int M) {
  constexpr int NKC = K / 32;
  constexpr int P = K + 8;  // u16 pitch
  __shared__ u16 Bs[NKC * 4 * 64 * 8];
  __shared__ u16 As[128 * P];
  int tid = threadIdx.x;
  bool isbf = (XMODE == 1) ? true : (flag[0] != 0);
#pragma unroll
  for (int i = 0; i < NKC; i++)
    ((uint4*)Bs)[i * 256 + tid] = ((const uint4*)Wb)[i * 256 + tid];

  int rowbase = blockIdx.x * 128;
  int rowsValid = M - rowbase; if (rowsValid > 128) rowsValid = 128;
  if (isbf) {
    constexpr int F8 = K / 8;
    const uint4* Xg = (const uint4*)X;
#pragma unroll
    for (int i = 0; i < K / 16; i++) {
      int q = i * 256 + tid;
      int row = q / F8, c8 = q % F8;
      uint4 v = (row < rowsValid) ? Xg[(size_t)(rowbase + row) * F8 + c8]
                                  : make_uint4(0, 0, 0, 0);
      *(uint4*)&As[row * P + c8 * 8] = v;
    }
  } else {
    constexpr int F4 = K / 4;
    const float4* Xg = (const float4*)X;
#pragma unroll
    for (int i = 0; i < K / 8; i++) {
      int q = i * 256 + tid;
      int row = q / F4, c4 = q % F4;
      float4 v = (row < rowsValid) ? Xg[(size_t)(rowbase + row) * F4 + c4]
                                   : make_float4(0.f, 0.f, 0.f, 0.f);
      u32* d = (u32*)&As[row * P + c4 * 4];
      d[0] = pack2(v.x, v.y);
      d[1] = pack2(v.z, v.w);
    }
  }
  __syncthreads();

  int lane = tid & 63, wave = tid >> 6;
  int m0 = lane & 15;
  int koff = (lane >> 4) * 8;
  f32x4 acc[2][4];
#pragma unroll
  for (int t = 0; t < 2; t++)
#pragma unroll
    for (int c = 0; c < 4; c++) acc[t][c] = (f32x4){0.f, 0.f, 0.f, 0.f};

#pragma unroll
  for (int kc = 0; kc < NKC; kc++) {
    union { uint4 v; bf16x8 s; } a[2];
#pragma unroll
    for (int t = 0; t < 2; t++) {
      int rl = wave * 32 + t * 16 + m0;
      a[t].v = *(const uint4*)&As[rl * P + kc * 32 + koff];
    }
#pragma unroll
    for (int c = 0; c < 4; c++) {
      bf16x8 b = *(const bf16x8*)&Bs[((kc * 4 + c) * 64 + lane) * 8];
      acc[0][c] = __builtin_amdgcn_mfma_f32_16x16x32_bf16(a[0].s, b, acc[0][c], 0, 0, 0);
      acc[1][c] = __builtin_amdgcn_mfma_f32_16x16x32_bf16(a[1].s, b, acc[1][c], 0, 0, 0);
    }
  }
  int cl = lane & 15, rq = (lane >> 4) * 4;
#pragma unroll
  for (int t = 0; t < 2; t++)
#pragma unroll
    for (int reg = 0; reg < 4; reg++) {
      int r = rowbase + wave * 32 + t * 16 + rq + reg;
      if (r < M) {
        float s = dinv[r];
#pragma unroll
        for (int c = 0; c < 4; c++)
          out[(size_t)r * 64 + c * 16 + cl] = f2bf(acc[t][c][reg] * s);
      }
    }
}

// ---------- pull: wave/node, uint4 gathers (8 edges/instr, 1 KB/instr) ----
// lane = (edge slot g8 = lane>>3, feature quad fq = lane&7). Each gather:
// 8 rows x 16B/lane. Edge-slot partials reduced by shfl_xor(8/16/32).
__global__ __launch_bounds__(256) void k_pull(const u16* __restrict__ g,
                                              const int* __restrict__ rp,
                                              const int* __restrict__ ss,
                                              const float* __restrict__ dinv,
                                              const float* __restrict__ bias,
                                              u16* __restrict__ out, int N) {
  int gt = blockIdx.x * 256 + threadIdx.x;
  int node = gt >> 6;
  int lane = gt & 63;
  if (node >= N) return;
  int g8 = lane >> 3;  // edge slot 0..7
  int fq = lane & 7;   // feature quad: features fq*8 .. fq*8+7
  const uint4* gp4 = (const uint4*)g;  // row = 8 uint4
  int beg = rp[node], end = rp[node + 1];
  float acc[8];
#pragma unroll
  for (int j = 0; j < 8; j++) acc[j] = 0.f;

  for (int base = beg; base < end; base += 64) {
    int iv = (base + lane < end) ? ss[base + lane] : 0;
    int m = end - base; if (m > 64) m = 64;
    int e = 0;
    for (; e + 16 <= m; e += 16) {  // 2 gathers = 16 edges in flight
      int i0 = __shfl(iv, e + g8);
      int i1 = __shfl(iv, e + 8 + g8);
      uint4 v0 = gp4[(size_t)i0 * 8 + fq];
      uint4 v1 = gp4[(size_t)i1 * 8 + fq];
      acc[0] += bf2f(v0.x & 0xffffu); acc[1] += bf2f(v0.x >> 16);
      acc[2] += bf2f(v0.y & 0xffffu); acc[3] += bf2f(v0.y >> 16);
      acc[4] += bf2f(v0.z & 0xffffu); acc[5] += bf2f(v0.z >> 16);
      acc[6] += bf2f(v0.w & 0xffffu); acc[7] += bf2f(v0.w >> 16);
      acc[0] += bf2f(v1.x & 0xffffu); acc[1] += bf2f(v1.x >> 16);
      acc[2] += bf2f(v1.y & 0xffffu); acc[3] += bf2f(v1.y >> 16);
      acc[4] += bf2f(v1.z & 0xffffu); acc[5] += bf2f(v1.z >> 16);
      acc[6] += bf2f(v1.w & 0xffffu); acc[7] += bf2f(v1.w >> 16);
    }
    if (e + 8 <= m) {  // one full 8-edge group
      int i0 = __shfl(iv, e + g8);
      uint4 v0 = gp4[(size_t)i0 * 8 + fq];
      acc[0] += bf2f(v0.x & 0xffffu); acc[1] += bf2f(v0.x >> 16);
      acc[2] += bf2f(v0.y & 0xffffu); acc[3] += bf2f(v0.y >> 16);
      acc[4] += bf2f(v0.z & 0xffffu); acc[5] += bf2f(v0.z >> 16);
      acc[6] += bf2f(v0.w & 0xffffu); acc[7] += bf2f(v0.w >> 16);
      e += 8;
    }
    if (e < m) {  // partial group: predicated per edge-slot
      int t = e + g8;
      int i0 = __shfl(iv, t < m ? t : e);  // safe src lane; add guarded
      if (t < m) {
        uint4 v0 = gp4[(size_t)i0 * 8 + fq];
        acc[0] += bf2f(v0.x & 0xffffu); acc[1] += bf2f(v0.x >> 16);
        acc[2] += bf2f(v0.y & 0xffffu); acc[3] += bf2f(v0.y >> 16);
        acc[4] += bf2f(v0.z & 0xffffu); acc[5] += bf2f(v0.z >> 16);
        acc[6] += bf2f(v0.w & 0xffffu); acc[7] += bf2f(v0.w >> 16);
      }
    }
  }
  // reduce edge-slot partials (stride 8, 16, 32)
#pragma unroll
  for (int j = 0; j < 8; j++) {
    acc[j] += __shfl_xor(acc[j], 8);
    acc[j] += __shfl_xor(acc[j], 16);
    acc[j] += __shfl_xor(acc[j], 32);
  }
  if (g8 == 0) {
    // self-loop term + bias + relu + bf16 store (8 lanes = 128B row)
    uint4 sv = gp4[(size_t)node * 8 + fq];
    acc[0] += bf2f(sv.x & 0xffffu); acc[1] += bf2f(sv.x >> 16);
    acc[2] += bf2f(sv.y & 0xffffu); acc[3] += bf2f(sv.y >> 16);
    acc[4] += bf2f(sv.z & 0xffffu); acc[5] += bf2f(sv.z >> 16);
    acc[6] += bf2f(sv.w & 0xffffu); acc[7] += bf2f(sv.w >> 16);
    float dv = dinv[node];
    float4 b0 = ((const float4*)bias)[fq * 2];
    float4 b1 = ((const float4*)bias)[fq * 2 + 1];
    float r0 = fmaxf(dv * acc[0] + b0.x, 0.f);
    float r1 = fmaxf(dv * acc[1] + b0.y, 0.f);
    float r2 = fmaxf(dv * acc[2] + b0.z, 0.f);
    float r3 = fmaxf(dv * acc[3] + b0.w, 0.f);
    float r4 = fmaxf(dv * acc[4] + b1.x, 0.f);
    float r5 = fmaxf(dv * acc[5] + b1.y, 0.f);
    float r6 = fmaxf(dv * acc[6] + b1.z, 0.f);
    float r7 = fmaxf(dv * acc[7] + b1.w, 0.f);
    ((uint4*)out)[(size_t)node * 8 + fq] =
        make_uint4(pack2(r0, r1), pack2(r2, r3), pack2(r4, r5), pack2(r6, r7));
  }
}

// ---------- head: MFMA [N,64]@[64,32] + bias + shfl-softmax ----------
__global__ __launch_bounds__(256) void k_out(const u16* __restrict__ act,
                                             const u16* __restrict__ Wbo,
                                             const float* __restrict__ bof,
                                             const int* __restrict__ flag,
                                             void* __restrict__ outv, int N) {
  constexpr int P = 72;  // 64+8 u16 pitch (144 B, 16B-aligned rows)
  __shared__ u16 Bs[2 * 2 * 64 * 8];   // 2048 u16 = 256 uint4
  __shared__ u16 As[128 * P];
  __shared__ float Bsh[32];
  int tid = threadIdx.x;
  ((uint4*)Bs)[tid] = ((const uint4*)Wbo)[tid];  // all 256 uint4
  if (tid < 32) Bsh[tid] = bof[tid];

  int rowbase = blockIdx.x * 128;
  int rowsValid = N - rowbase; if (rowsValid > 128) rowsValid = 128;
  const uint4* Xg = (const uint4*)act;
#pragma unroll
  for (int i = 0; i < 4; i++) {
    int q = i * 256 + tid;
    int row = q >> 3, c8 = q & 7;
    uint4 v = (row < rowsValid) ? Xg[(size_t)(rowbase + row) * 8 + c8]
                                : make_uint4(0, 0, 0, 0);
    *(uint4*)&As[row * P + c8 * 8] = v;
  }
  __syncthreads();

  bool isbf = flag[0] != 0;
  int lane = tid & 63, wave = tid >> 6;
  int m0 = lane & 15;
  int koff = (lane >> 4) * 8;
  f32x4 acc[2][2];
#pragma unroll
  for (int t = 0; t < 2; t++)
#pragma unroll
    for (int c = 0; c < 2; c++) acc[t][c] = (f32x4){0.f, 0.f, 0.f, 0.f};

#pragma unroll
  for (int kc = 0; kc < 2; kc++) {
    union { uint4 v; bf16x8 s; } a[2];
#pragma unroll
    for (int t = 0; t < 2; t++) {
      int rl = wave * 32 + t * 16 + m0;
      a[t].v = *(const uint4*)&As[rl * P + kc * 32 + koff];
    }
#pragma unroll
    for (int c = 0; c < 2; c++) {
      bf16x8 b = *(const bf16x8*)&Bs[((kc * 2 + c) * 64 + lane) * 8];
      acc[0][c] = __builtin_amdgcn_mfma_f32_16x16x32_bf16(a[0].s, b, acc[0][c], 0, 0, 0);
      acc[1][c] = __builtin_amdgcn_mfma_f32_16x16x32_bf16(a[1].s, b, acc[1][c], 0, 0, 0);
    }
  }
  int cl = lane & 15, rq = (lane >> 4) * 4;
  float b0 = Bsh[cl], b1 = Bsh[16 + cl];
#pragma unroll
  for (int t = 0; t < 2; t++)
#pragma unroll
    for (int reg = 0; reg < 4; reg++) {
      int r = rowbase + wave * 32 + t * 16 + rq + reg;
      float v0 = acc[t][0][reg] + b0;
      float v1 = acc[t][1][reg] + b1;
      float mx = fmaxf(v0, v1);
      mx = fmaxf(mx, __shfl_xor(mx, 1));
      mx = fmaxf(mx, __shfl_xor(mx, 2));
      mx = fmaxf(mx, __shfl_xor(mx, 4));
      mx = fmaxf(mx, __shfl_xor(mx, 8));
      float e0 = __expf(v0 - mx), e1 = __expf(v1 - mx);
      float s = e0 + e1;
      s += __shfl_xor(s, 1);
      s += __shfl_xor(s, 2);
      s += __shfl_xor(s, 4);
      s += __shfl_xor(s, 8);
      float inv = 1.f / s;
      if (r < N) {
        if (isbf) {
          u16* go = (u16*)outv;
          go[(size_t)r * 32 + cl]      = f2bf(e0 * inv);
          go[(size_t)r * 32 + 16 + cl] = f2bf(e1 * inv);
        } else {
          float* go = (float*)outv;
          go[(size_t)r * 32 + cl]      = e0 * inv;
          go[(size_t)r * 32 + 16 + cl] = e1 * inv;
        }
      }
    }
}

extern "C" void kernel_launch(void* const* d_in, const int* in_sizes, int n_in,
                              void* d_out, int out_size, void* d_ws, size_t ws_size,
                              hipStream_t stream) {
  (void)in_sizes; (void)n_in; (void)out_size; (void)ws_size;
  const void* x  = d_in[0];              // [N,128] fp32 (observed) or bf16
  const int* ei  = (const int*)d_in[1];  // [2,E]
  const int N = GN, E = GE;
  const int* srcI = ei;
  const int* dstI = ei + E;

  char* ws = (char*)d_ws;
  int*   flag   = (int*)(ws + 0);
  int*   ccount = (int*)(ws + 256);       // 196 ints
  int*   cbase  = (int*)(ws + 1088);      // 197 ints
  int*   cfill  = (int*)(ws + 1920);      // 196 ints
  int*   rp     = (int*)(ws + 4096);      // N+1 ints
  float* dinv   = (float*)(ws + 404224);  // N floats
  float* Wf     = (float*)(ws + 804352);  // 14496 floats
  u16*   Wb1    = (u16*)(ws + 862464);    // 8192 u16 (16 KB)
  u16*   Wb2    = (u16*)(ws + 878848);    // 4096 u16 (8 KB)
  u16*   Wbo    = (u16*)(ws + 887040);    // 2048 u16 (4 KB)
  int*   ssort  = (int*)(ws + 891136);    // E ints (6.4 MB)
  uint2* pairs  = (uint2*)(ws + 7291136); // E uint2 (12.8 MB)
  u16*   gA     = (u16*)(ws + 7291136);   // N*64 bf16 — OVERLAYS pairs (dead)
  u16*   gB     = (u16*)(ws + 20091136);  // N*64 bf16 (12.8 MB)
  // total = 32891136 bytes (~32.9 MB)

  float* b1f = Wf + 8192;
  float* b2f = Wf + 12352;
  float* bof = Wf + 14464;

  k_detect<<<1, 256, 0, stream>>>((const u16*)x, flag, ccount);
  k_coarse<<<782, 256, 0, stream>>>(dstI, ccount, E);
  k_cscan<<<1, 256, 0, stream>>>(ccount, cbase, cfill);
  k_partA<<<782, 256, 0, stream>>>(srcI, dstI, cfill, pairs, E);
  k_partB<<<NBKT, 256, 0, stream>>>(pairs, cbase, rp, dinv, ssort, N);
  k_wprep2<<<113, 256, 0, stream>>>(d_in[2], d_in[3], d_in[4], d_in[5],
                                    d_in[6], d_in[7], flag, Wf, Wb1, Wb2, Wbo);

  k_mgemm<128, 0><<<782, 256, 0, stream>>>(x, Wb1, dinv, flag, gA, N);
  k_pull<<<25000, 256, 0, stream>>>(gA, rp, ssort, dinv, b1f, gB, N);
  k_mgemm<64, 1><<<782, 256, 0, stream>>>(gB, Wb2, dinv, flag, gA, N);
  k_pull<<<25000, 256, 0, stream>>>(gA, rp, ssort, dinv, b2f, gB, N);
  k_out<<<782, 256, 0, stream>>>(gB, Wbo, bof, flag, d_out, N);
}

// Round 11
// 289.508 us; speedup vs baseline: 1.0414x; 1.0414x over previous
//
#include <hip/hip_runtime.h>
#include <stdint.h>

// GCN on MI355X, graph-capture safe. Dataset observed fp32 (flag=0);
// bf16 path kept. Pipeline: detect -> coarse+wprep (merged dispatch)
// -> cscan -> partA (radix partition, u32-packed pairs) -> partB
// (per-bucket CSR) -> mgemm1 (bf16 MFMA, 2-phase staged A, LDS-
// transposed coalesced C-store) -> pull1 -> mgemm2 -> pull2 -> k_out.
// R11: mgemm C through LDS (fix 32-B scatter stores), 2-phase staging,
// pairs packed to u32 (src<<9|dstlo), wprep merged into coarse.

typedef unsigned short u16;
typedef unsigned int u32;
typedef __attribute__((ext_vector_type(8))) short bf16x8;
typedef __attribute__((ext_vector_type(4))) float f32x4;

#define GN 100000
#define GE 1600000
#define NBKT 196   // ceil(100000/512)
#define CBLK 782   // coarse blocks in merged dispatch

__device__ __forceinline__ float bf2f(u32 lo16) {
  union { u32 i; float f; } v; v.i = lo16 << 16; return v.f;
}
__device__ __forceinline__ u16 f2bf(float f) {
  union { float f; u32 i; } v; v.f = f;
  u32 x = v.i;
  u32 r = x + 0x7fffu + ((x >> 16) & 1u);  // RNE
  return (u16)(r >> 16);
}
__device__ __forceinline__ u32 pack2(float a, float b) {
  return (u32)f2bf(a) | ((u32)f2bf(b) << 16);
}

// ---------- dtype sniff (flag=1 -> bf16) + zero coarse counters ----------
__global__ __launch_bounds__(256) void k_detect(const u16* __restrict__ xs,
                                                int* __restrict__ flag,
                                                int* __restrict__ ccount) {
  __shared__ int cnt;
  if (threadIdx.x == 0) cnt = 0;
  if (threadIdx.x < NBKT) ccount[threadIdx.x] = 0;
  __syncthreads();
  int w = 0;
#pragma unroll
  for (int i = 0; i < 16; i++) {
    int s = threadIdx.x * 16 + i;
    u32 u = xs[(size_t)s * 1562];
    u32 ex = (u >> 7) & 0xffu;
    if (ex == 0xffu || ex < 0x40u) w++;
  }
  atomicAdd(&cnt, w);
  __syncthreads();
  if (threadIdx.x == 0) flag[0] = (cnt >= 64) ? 0 : 1;
}

// ---------- merged: coarse histogram (blocks < CBLK) + weight prep ----------
// wprep blob: W1 8192 | b1 64 | W2 4096 | b2 64 | Wout 2048 | bout 32 = 14496
// Wb1/Wb2: frag[((kc*4+c)*64+l)*8+j] = W[kc*32+(l>>4)*8+j][c*16+(l&15)]
// Wbo:     frag[((kc*2+c)*64+l)*8+j] = Wout[kc*32+(l>>4)*8+j][c*16+(l&15)]
__global__ __launch_bounds__(256) void k_coarse(const int* __restrict__ dst,
                                                int* __restrict__ ccount, int E,
                                                const void* p2, const void* p3,
                                                const void* p4, const void* p5,
                                                const void* p6, const void* p7,
                                                const int* __restrict__ flag,
                                                float* __restrict__ Wf,
                                                u16* __restrict__ Wb1,
                                                u16* __restrict__ Wb2,
                                                u16* __restrict__ Wbo) {
  int tid = threadIdx.x;
  if (blockIdx.x >= CBLK) {
    // ---- weight prep part ----
    int i = (blockIdx.x - CBLK) * 256 + tid;
    bool isbf = flag[0] != 0;
    if (i < 14496) {
      const void* src; int off;
      if (i < 8192)       { src = p2; off = i; }
      else if (i < 8256)  { src = p3; off = i - 8192; }
      else if (i < 12352) { src = p4; off = i - 8256; }
      else if (i < 12416) { src = p5; off = i - 12352; }
      else if (i < 14464) { src = p6; off = i - 12416; }
      else                { src = p7; off = i - 14464; }
      Wf[i] = isbf ? bf2f((u32)((const u16*)src)[off]) : ((const float*)src)[off];
    } else if (i < 14496 + 12288) {
      int idx = i - 14496;
      const void* W; u16* dstp;
      if (idx < 8192) { W = p2; dstp = Wb1; }
      else            { W = p4; dstp = Wb2; idx -= 8192; }
      int j  = idx & 7;
      int l  = (idx >> 3) & 63;
      int c  = (idx >> 9) & 3;
      int kc = idx >> 11;
      int k = kc * 32 + (l >> 4) * 8 + j;
      int n = c * 16 + (l & 15);
      dstp[idx] = isbf ? ((const u16*)W)[k * 64 + n]
                       : f2bf(((const float*)W)[k * 64 + n]);
    } else if (i < 14496 + 12288 + 2048) {
      int idx = i - 14496 - 12288;
      int j  = idx & 7;
      int l  = (idx >> 3) & 63;
      int c  = (idx >> 9) & 1;
      int kc = idx >> 10;
      int k = kc * 32 + (l >> 4) * 8 + j;
      int n = c * 16 + (l & 15);
      Wbo[idx] = isbf ? ((const u16*)p6)[k * 32 + n]
                      : f2bf(((const float*)p6)[k * 32 + n]);
    }
    return;
  }
  // ---- coarse histogram part ----
  __shared__ int hist[256];
  hist[tid] = 0;
  __syncthreads();
  int e0 = (blockIdx.x * 256 + tid) * 8;
  if (e0 + 8 <= E) {
    const int4* dp = (const int4*)(dst + e0);
    int4 a = dp[0], b = dp[1];
    atomicAdd(&hist[a.x >> 9], 1); atomicAdd(&hist[a.y >> 9], 1);
    atomicAdd(&hist[a.z >> 9], 1); atomicAdd(&hist[a.w >> 9], 1);
    atomicAdd(&hist[b.x >> 9], 1); atomicAdd(&hist[b.y >> 9], 1);
    atomicAdd(&hist[b.z >> 9], 1); atomicAdd(&hist[b.w >> 9], 1);
  } else {
    for (int q = 0; q < 8 && e0 + q < E; q++)
      atomicAdd(&hist[dst[e0 + q] >> 9], 1);
  }
  __syncthreads();
  if (tid < NBKT && hist[tid]) atomicAdd(&ccount[tid], hist[tid]);
}

// ---------- scan coarse counts -> cbase (exclusive), cfill ----------
__global__ __launch_bounds__(256) void k_cscan(const int* __restrict__ ccount,
                                               int* __restrict__ cbase,
                                               int* __restrict__ cfill) {
  __shared__ int lds[256];
  int tid = threadIdx.x;
  int v = (tid < NBKT) ? ccount[tid] : 0;
  lds[tid] = v;
  __syncthreads();
#pragma unroll
  for (int off = 1; off < 256; off <<= 1) {
    int a = (tid >= off) ? lds[tid - off] : 0;
    __syncthreads();
    lds[tid] += a;
    __syncthreads();
  }
  int excl = lds[tid] - v;
  if (tid < NBKT) { cbase[tid] = excl; cfill[tid] = excl; }
  if (tid == 255) cbase[NBKT] = lds[255];  // == E
}

// ---------- phase A: partition edges into bucket regions, u32-packed ------
// pair = (src << 9) | (dst & 511); src < 2^17, dst-local < 2^9.
__global__ __launch_bounds__(256) void k_partA(const int* __restrict__ src,
                                               const int* __restrict__ dst,
                                               int* __restrict__ cfill,
                                               u32* __restrict__ pairs, int E) {
  __shared__ int hist[256];
  __shared__ int off[256];
  int tid = threadIdx.x;
  hist[tid] = 0;
  __syncthreads();
  int e0 = (blockIdx.x * 256 + tid) * 8;
  int s_[8], d_[8];
  int cnt = 0;
  if (e0 + 8 <= E) {
    const int4* sp = (const int4*)(src + e0);
    const int4* dp = (const int4*)(dst + e0);
#pragma unroll
    for (int q = 0; q < 2; q++) {
      int4 sv = sp[q], dv = dp[q];
      s_[4 * q + 0] = sv.x; s_[4 * q + 1] = sv.y;
      s_[4 * q + 2] = sv.z; s_[4 * q + 3] = sv.w;
      d_[4 * q + 0] = dv.x; d_[4 * q + 1] = dv.y;
      d_[4 * q + 2] = dv.z; d_[4 * q + 3] = dv.w;
    }
    cnt = 8;
  } else {
    for (int q = 0; q < 8 && e0 + q < E; q++) {
      s_[q] = src[e0 + q]; d_[q] = dst[e0 + q]; cnt++;
    }
  }
  for (int q = 0; q < cnt; q++) atomicAdd(&hist[d_[q] >> 9], 1);
  __syncthreads();
  if (tid < NBKT && hist[tid] > 0) off[tid] = atomicAdd(&cfill[tid], hist[tid]);
  __syncthreads();
  for (int q = 0; q < cnt; q++) {
    int bkt = d_[q] >> 9;
    int pos = atomicAdd(&off[bkt], 1);
    pairs[pos] = ((u32)s_[q] << 9) | ((u32)d_[q] & 511u);
  }
}

// ---------- phase B: per-bucket node hist + scan -> rp/dinv; place ssort ---
__global__ __launch_bounds__(256) void k_partB(const u32* __restrict__ pairs,
                                               const int* __restrict__ cbase,
                                               int* __restrict__ rp,
                                               float* __restrict__ dinv,
                                               int* __restrict__ ssort, int N) {
  __shared__ int cnt[512];
  __shared__ int sc[256];
  int b = blockIdx.x;
  int tid = threadIdx.x;
  int nb0 = b << 9;
  int beg = cbase[b], end = cbase[b + 1];
  cnt[tid] = 0; cnt[tid + 256] = 0;
  __syncthreads();
  for (int i = beg + tid; i < end; i += 256) {
    u32 p = pairs[i];
    atomicAdd(&cnt[p & 511u], 1);
  }
  __syncthreads();
  int c0 = cnt[2 * tid], c1 = cnt[2 * tid + 1];
  int s = c0 + c1;
  sc[tid] = s;
  __syncthreads();
#pragma unroll
  for (int off = 1; off < 256; off <<= 1) {
    int a = (tid >= off) ? sc[tid - off] : 0;
    __syncthreads();
    sc[tid] += a;
    __syncthreads();
  }
  int excl = sc[tid] - s;
  cnt[2 * tid] = excl;
  cnt[2 * tid + 1] = excl + c0;
  int n0 = nb0 + 2 * tid, n1 = n0 + 1;
  if (n0 < N) { rp[n0] = beg + excl;      dinv[n0] = rsqrtf((float)c0 + 1.0f); }
  if (n1 < N) { rp[n1] = beg + excl + c0; dinv[n1] = rsqrtf((float)c1 + 1.0f); }
  if (b == NBKT - 1 && tid == 0) rp[N] = end;
  __syncthreads();
  for (int i = beg + tid; i < end; i += 256) {
    u32 p = pairs[i];
    int pos = beg + atomicAdd(&cnt[p & 511u], 1);
    ssort[pos] = (int)(p >> 9);
  }
}

// ---------- MFMA GEMM: out[M,64] = bf16(dinv .* (X[M,K]@W[K,64])) ----------
// 2-phase staging (all loads -> regs, then cvt -> LDS) for load ILP.
// C bounced through As (dead after MFMA) -> coalesced uint4 row stores.
template <int K, int XMODE>
__global__ __launch_bounds__(256) void k_mgemm(const void* __restrict__ X,
                                               const u16* __restrict__ Wb,
                                               const float* __restrict__ dinv,
                                               const int* __restrict__ flag,
                                               u16* __restrict__ out, int M) {
  constexpr int NKC = K / 32;
  constexpr int P = K + 8;  // u16 pitch
  __shared__ u16 Bs[NKC * 4 * 64 * 8];
  __shared__ u16 As[128 * P];
  int tid = threadIdx.x;
  bool isbf = (XMODE == 1) ? true : (flag[0] != 0);
#pragma unroll
  for (int i = 0; i < NKC; i++)
    ((uint4*)Bs)[i * 256 + tid] = ((const uint4*)Wb)[i * 256 + tid];

  int rowbase = blockIdx.x * 128;
  int rowsValid = M - rowbase; if (rowsValid > 128) rowsValid = 128;
  if (isbf) {
    constexpr int F8 = K / 8;   // uint4 per row
    constexpr int NL = K / 16;  // uint4 per thread
    const uint4* Xg = (const uint4*)X;
    uint4 v[NL];
#pragma unroll
    for (int i = 0; i < NL; i++) {
      int q = i * 256 + tid;
      int row = q / F8, c8 = q % F8;
      v[i] = (row < rowsValid) ? Xg[(size_t)(rowbase + row) * F8 + c8]
                               : make_uint4(0, 0, 0, 0);
    }
#pragma unroll
    for (int i = 0; i < NL; i++) {
      int q = i * 256 + tid;
      int row = q / F8, c8 = q % F8;
      *(uint4*)&As[row * P + c8 * 8] = v[i];
    }
  } else {
    constexpr int F4 = K / 4;   // float4 per row
    constexpr int NL = K / 8;   // float4 per thread
    const float4* Xg = (const float4*)X;
    float4 v[NL];
#pragma unroll
    for (int i = 0; i < NL; i++) {
      int q = i * 256 + tid;
      int row = q / F4, c4 = q % F4;
      v[i] = (row < rowsValid) ? Xg[(size_t)(rowbase + row) * F4 + c4]
                               : make_float4(0.f, 0.f, 0.f, 0.f);
    }
#pragma unroll
    for (int i = 0; i < NL; i++) {
      int q = i * 256 + tid;
      int row = q / F4, c4 = q % F4;
      u32* d = (u32*)&As[row * P + c4 * 4];
      d[0] = pack2(v[i].x, v[i].y);
      d[1] = pack2(v[i].z, v[i].w);
    }
  }
  __syncthreads();

  int lane = tid & 63, wave = tid >> 6;
  int m0 = lane & 15;
  int koff = (lane >> 4) * 8;
  f32x4 acc[2][4];
#pragma unroll
  for (int t = 0; t < 2; t++)
#pragma unroll
    for (int c = 0; c < 4; c++) acc[t][c] = (f32x4){0.f, 0.f, 0.f, 0.f};

#pragma unroll
  for (int kc = 0; kc < NKC; kc++) {
    union { uint4 v; bf16x8 s; } a[2];
#pragma unroll
    for (int t = 0; t < 2; t++) {
      int rl = wave * 32 + t * 16 + m0;
      a[t].v = *(const uint4*)&As[rl * P + kc * 32 + koff];
    }
#pragma unroll
    for (int c = 0; c < 4; c++) {
      bf16x8 b = *(const bf16x8*)&Bs[((kc * 4 + c) * 64 + lane) * 8];
      acc[0][c] = __builtin_amdgcn_mfma_f32_16x16x32_bf16(a[0].s, b, acc[0][c], 0, 0, 0);
      acc[1][c] = __builtin_amdgcn_mfma_f32_16x16x32_bf16(a[1].s, b, acc[1][c], 0, 0, 0);
    }
  }
  // Epilogue: write C into As (rows in output layout), then coalesced store.
  __syncthreads();  // all As fragment reads complete before overwrite
  int cl = lane & 15, rq = (lane >> 4) * 4;
#pragma unroll
  for (int t = 0; t < 2; t++)
#pragma unroll
    for (int reg = 0; reg < 4; reg++) {
      int rl = wave * 32 + t * 16 + rq + reg;
      int r = rowbase + rl;
      float s = (r < M) ? dinv[r] : 0.f;
#pragma unroll
      for (int c = 0; c < 4; c++)
        As[rl * P + c * 16 + cl] = f2bf(acc[t][c][reg] * s);
    }
  __syncthreads();
  uint4* outg = (uint4*)out;
#pragma unroll
  for (int i = 0; i < 4; i++) {
    int q = i * 256 + tid;
    int row = q >> 3, c8 = q & 7;
    int r = rowbase + row;
    if (r < M) outg[(size_t)r * 8 + c8] = *(uint4*)&As[row * P + c8 * 8];
  }
}

// ---------- pull: wave/node, uint4 gathers (8 edges/instr, 1 KB/instr) ----
__global__ __launch_bounds__(256) void k_pull(const u16* __restrict__ g,
                                              const int* __restrict__ rp,
                                              const int* __restrict__ ss,
                                              const float* __restrict__ dinv,
                                              const float* __restrict__ bias,
                                              u16* __restrict__ out, int N) {
  int gt = blockIdx.x * 256 + threadIdx.x;
  int node = gt >> 6;
  int lane = gt & 63;
  if (node >= N) return;
  int g8 = lane >> 3;  // edge slot 0..7
  int fq = lane & 7;   // feature quad: features fq*8 .. fq*8+7
  const uint4* gp4 = (const uint4*)g;  // row = 8 uint4
  int beg = rp[node], end = rp[node + 1];
  float acc[8];
#pragma unroll
  for (int j = 0; j < 8; j++) acc[j] = 0.f;

  for (int base = beg; base < end; base += 64) {
    int iv = (base + lane < end) ? ss[base + lane] : 0;
    int m = end - base; if (m > 64) m = 64;
    int e = 0;
    for (; e + 16 <= m; e += 16) {
      int i0 = __shfl(iv, e + g8);
      int i1 = __shfl(iv, e + 8 + g8);
      uint4 v0 = gp4[(size_t)i0 * 8 + fq];
      uint4 v1 = gp4[(size_t)i1 * 8 + fq];
      acc[0] += bf2f(v0.x & 0xffffu); acc[1] += bf2f(v0.x >> 16);
      acc[2] += bf2f(v0.y & 0xffffu); acc[3] += bf2f(v0.y >> 16);
      acc[4] += bf2f(v0.z & 0xffffu); acc[5] += bf2f(v0.z >> 16);
      acc[6] += bf2f(v0.w & 0xffffu); acc[7] += bf2f(v0.w >> 16);
      acc[0] += bf2f(v1.x & 0xffffu); acc[1] += bf2f(v1.x >> 16);
      acc[2] += bf2f(v1.y & 0xffffu); acc[3] += bf2f(v1.y >> 16);
      acc[4] += bf2f(v1.z & 0xffffu); acc[5] += bf2f(v1.z >> 16);
      acc[6] += bf2f(v1.w & 0xffffu); acc[7] += bf2f(v1.w >> 16);
    }
    if (e + 8 <= m) {
      int i0 = __shfl(iv, e + g8);
      uint4 v0 = gp4[(size_t)i0 * 8 + fq];
      acc[0] += bf2f(v0.x & 0xffffu); acc[1] += bf2f(v0.x >> 16);
      acc[2] += bf2f(v0.y & 0xffffu); acc[3] += bf2f(v0.y >> 16);
      acc[4] += bf2f(v0.z & 0xffffu); acc[5] += bf2f(v0.z >> 16);
      acc[6] += bf2f(v0.w & 0xffffu); acc[7] += bf2f(v0.w >> 16);
      e += 8;
    }
    if (e < m) {
      int t = e + g8;
      int i0 = __shfl(iv, t < m ? t : e);
      if (t < m) {
        uint4 v0 = gp4[(size_t)i0 * 8 + fq];
        acc[0] += bf2f(v0.x & 0xffffu); acc[1] += bf2f(v0.x >> 16);
        acc[2] += bf2f(v0.y & 0xffffu); acc[3] += bf2f(v0.y >> 16);
        acc[4] += bf2f(v0.z & 0xffffu); acc[5] += bf2f(v0.z >> 16);
        acc[6] += bf2f(v0.w & 0xffffu); acc[7] += bf2f(v0.w >> 16);
      }
    }
  }
#pragma unroll
  for (int j = 0; j < 8; j++) {
    acc[j] += __shfl_xor(acc[j], 8);
    acc[j] += __shfl_xor(acc[j], 16);
    acc[j] += __shfl_xor(acc[j], 32);
  }
  if (g8 == 0) {
    uint4 sv = gp4[(size_t)node * 8 + fq];
    acc[0] += bf2f(sv.x & 0xffffu); acc[1] += bf2f(sv.x >> 16);
    acc[2] += bf2f(sv.y & 0xffffu); acc[3] += bf2f(sv.y >> 16);
    acc[4] += bf2f(sv.z & 0xffffu); acc[5] += bf2f(sv.z >> 16);
    acc[6] += bf2f(sv.w & 0xffffu); acc[7] += bf2f(sv.w >> 16);
    float dv = dinv[node];
    float4 b0 = ((const float4*)bias)[fq * 2];
    float4 b1 = ((const float4*)bias)[fq * 2 + 1];
    float r0 = fmaxf(dv * acc[0] + b0.x, 0.f);
    float r1 = fmaxf(dv * acc[1] + b0.y, 0.f);
    float r2 = fmaxf(dv * acc[2] + b0.z, 0.f);
    float r3 = fmaxf(dv * acc[3] + b0.w, 0.f);
    float r4 = fmaxf(dv * acc[4] + b1.x, 0.f);
    float r5 = fmaxf(dv * acc[5] + b1.y, 0.f);
    float r6 = fmaxf(dv * acc[6] + b1.z, 0.f);
    float r7 = fmaxf(dv * acc[7] + b1.w, 0.f);
    ((uint4*)out)[(size_t)node * 8 + fq] =
        make_uint4(pack2(r0, r1), pack2(r2, r3), pack2(r4, r5), pack2(r6, r7));
  }
}

// ---------- head: MFMA [N,64]@[64,32] + bias + shfl-softmax ----------
__global__ __launch_bounds__(256) void k_out(const u16* __restrict__ act,
                                             const u16* __restrict__ Wbo,
                                             const float* __restrict__ bof,
                                             const int* __restrict__ flag,
                                             void* __restrict__ outv, int N) {
  constexpr int P = 72;  // 64+8 u16 pitch
  __shared__ u16 Bs[2 * 2 * 64 * 8];   // 2048 u16 = 256 uint4
  __shared__ u16 As[128 * P];
  __shared__ float Bsh[32];
  int tid = threadIdx.x;
  ((uint4*)Bs)[tid] = ((const uint4*)Wbo)[tid];
  if (tid < 32) Bsh[tid] = bof[tid];

  int rowbase = blockIdx.x * 128;
  int rowsValid = N - rowbase; if (rowsValid > 128) rowsValid = 128;
  const uint4* Xg = (const uint4*)act;
#pragma unroll
  for (int i = 0; i < 4; i++) {
    int q = i * 256 + tid;
    int row = q >> 3, c8 = q & 7;
    uint4 v = (row < rowsValid) ? Xg[(size_t)(rowbase + row) * 8 + c8]
                                : make_uint4(0, 0, 0, 0);
    *(uint4*)&As[row * P + c8 * 8] = v;
  }
  __syncthreads();

  bool isbf = flag[0] != 0;
  int lane = tid & 63, wave = tid >> 6;
  int m0 = lane & 15;
  int koff = (lane >> 4) * 8;
  f32x4 acc[2][2];
#pragma unroll
  for (int t = 0; t < 2; t++)
#pragma unroll
    for (int c = 0; c < 2; c++) acc[t][c] = (f32x4){0.f, 0.f, 0.f, 0.f};

#pragma unroll
  for (int kc = 0; kc < 2; kc++) {
    union { uint4 v; bf16x8 s; } a[2];
#pragma unroll
    for (int t = 0; t < 2; t++) {
      int rl = wave * 32 + t * 16 + m0;
      a[t].v = *(const uint4*)&As[rl * P + kc * 32 + koff];
    }
#pragma unroll
    for (int c = 0; c < 2; c++) {
      bf16x8 b = *(const bf16x8*)&Bs[((kc * 2 + c) * 64 + lane) * 8];
      acc[0][c] = __builtin_amdgcn_mfma_f32_16x16x32_bf16(a[0].s, b, acc[0][c], 0, 0, 0);
      acc[1][c] = __builtin_amdgcn_mfma_f32_16x16x32_bf16(a[1].s, b, acc[1][c], 0, 0, 0);
    }
  }
  int cl = lane & 15, rq = (lane >> 4) * 4;
  float b0 = Bsh[cl], b1 = Bsh[16 + cl];
#pragma unroll
  for (int t = 0; t < 2; t++)
#pragma unroll
    for (int reg = 0; reg < 4; reg++) {
      int r = rowbase + wave * 32 + t * 16 + rq + reg;
      float v0 = acc[t][0][reg] + b0;
      float v1 = acc[t][1][reg] + b1;
      float mx = fmaxf(v0, v1);
      mx = fmaxf(mx, __shfl_xor(mx, 1));
      mx = fmaxf(mx, __shfl_xor(mx, 2));
      mx = fmaxf(mx, __shfl_xor(mx, 4));
      mx = fmaxf(mx, __shfl_xor(mx, 8));
      float e0 = __expf(v0 - mx), e1 = __expf(v1 - mx);
      float s = e0 + e1;
      s += __shfl_xor(s, 1);
      s += __shfl_xor(s, 2);
      s += __shfl_xor(s, 4);
      s += __shfl_xor(s, 8);
      float inv = 1.f / s;
      if (r < N) {
        if (isbf) {
          u16* go = (u16*)outv;
          go[(size_t)r * 32 + cl]      = f2bf(e0 * inv);
          go[(size_t)r * 32 + 16 + cl] = f2bf(e1 * inv);
        } else {
          float* go = (float*)outv;
          go[(size_t)r * 32 + cl]      = e0 * inv;
          go[(size_t)r * 32 + 16 + cl] = e1 * inv;
        }
      }
    }
}

extern "C" void kernel_launch(void* const* d_in, const int* in_sizes, int n_in,
                              void* d_out, int out_size, void* d_ws, size_t ws_size,
                              hipStream_t stream) {
  (void)in_sizes; (void)n_in; (void)out_size; (void)ws_size;
  const void* x  = d_in[0];              // [N,128] fp32 (observed) or bf16
  const int* ei  = (const int*)d_in[1];  // [2,E]
  const int N = GN, E = GE;
  const int* srcI = ei;
  const int* dstI = ei + E;

  char* ws = (char*)d_ws;
  int*   flag   = (int*)(ws + 0);
  int*   ccount = (int*)(ws + 256);       // 196 ints
  int*   cbase  = (int*)(ws + 1088);      // 197 ints
  int*   cfill  = (int*)(ws + 1920);      // 196 ints
  int*   rp     = (int*)(ws + 4096);      // N+1 ints
  float* dinv   = (float*)(ws + 404224);  // N floats
  float* Wf     = (float*)(ws + 804352);  // 14496 floats
  u16*   Wb1    = (u16*)(ws + 862464);    // 8192 u16 (16 KB)
  u16*   Wb2    = (u16*)(ws + 878848);    // 4096 u16 (8 KB)
  u16*   Wbo    = (u16*)(ws + 887040);    // 2048 u16 (4 KB)
  int*   ssort  = (int*)(ws + 891136);    // E ints (6.4 MB)
  u32*   pairs  = (u32*)(ws + 7291136);   // E u32 (6.4 MB, packed)
  u16*   gA     = (u16*)(ws + 7291136);   // N*64 bf16 — OVERLAYS pairs (dead)
  u16*   gB     = (u16*)(ws + 20091136);  // N*64 bf16 (12.8 MB)
  // total = 32891136 bytes (~32.9 MB)

  float* b1f = Wf + 8192;
  float* b2f = Wf + 12352;
  float* bof = Wf + 14464;

  k_detect<<<1, 256, 0, stream>>>((const u16*)x, flag, ccount);
  k_coarse<<<CBLK + 113, 256, 0, stream>>>(dstI, ccount, E,
                                           d_in[2], d_in[3], d_in[4], d_in[5],
                                           d_in[6], d_in[7], flag,
                                           Wf, Wb1, Wb2, Wbo);
  k_cscan<<<1, 256, 0, stream>>>(ccount, cbase, cfill);
  k_partA<<<782, 256, 0, stream>>>(srcI, dstI, cfill, pairs, E);
  k_partB<<<NBKT, 256, 0, stream>>>(pairs, cbase, rp, dinv, ssort, N);

  k_mgemm<128, 0><<<782, 256, 0, stream>>>(x, Wb1, dinv, flag, gA, N);
  k_pull<<<25000, 256, 0, stream>>>(gA, rp, ssort, dinv, b1f, gB, N);
  k_mgemm<64, 1><<<782, 256, 0, stream>>>(gB, Wb2, dinv, flag, gA, N);
  k_pull<<<25000, 256, 0, stream>>>(gA, rp, ssort, dinv, b2f, gB, N);
  k_out<<<782, 256, 0, stream>>>(gB, Wbo, bof, flag, d_out, N);
}